// Round 2
// 688.574 us; speedup vs baseline: 1.0449x; 1.0449x over previous
//
#include <hip/hip_runtime.h>
#include <hip/hip_bf16.h>

#define B_      32
#define HID_    2048
#define INNER_  4096
#define NH_     8
#define HEAD_   512
#define CAP_    30.0f
#define DCH_    64          // d-rows per cell-stream block

typedef short short8 __attribute__((ext_vector_type(8)));
typedef float f32x4 __attribute__((ext_vector_type(4)));

static __device__ __forceinline__ unsigned short f2bf(float f) {
    unsigned int u = __float_as_uint(f);
    u = (u + 0x7fffu + ((u >> 16) & 1u)) >> 16;   // RNE
    return (unsigned short)u;
}

static __device__ __forceinline__ float sigm(float x) { return 1.0f / (1.0f + expf(-x)); }
static __device__ __forceinline__ float silu(float x) { return x * sigm(x); }

// ---------------------------------------------------------------------------
// RMSNorm: xn = x * rsqrt(mean(x^2)+eps) * rms_w      (B blocks)
// ---------------------------------------------------------------------------
__global__ void k_rms(const float* __restrict__ x, const float* __restrict__ rms_w,
                      float* __restrict__ xn) {
    const int b = blockIdx.x, t = threadIdx.x;
    __shared__ float red[4];
    const float* xr = x + b * HID_;
    float s = 0.f;
    for (int i = t; i < HID_; i += 256) { float v = xr[i]; s += v * v; }
    for (int off = 32; off; off >>= 1) s += __shfl_down(s, off, 64);
    if ((t & 63) == 0) red[t >> 6] = s;
    __syncthreads();
    const float scale = rsqrtf((red[0] + red[1] + red[2] + red[3]) / (float)HID_ + 1e-6f);
    float* xo = xn + b * HID_;
    for (int i = t; i < HID_; i += 256) xo[i] = xr[i] * scale * rms_w[i];
}

// ---------------------------------------------------------------------------
// Skinny GEMM: Cp[split][32][N] = A[32][K] @ W[N][K]^T  (bf16 MFMA 16x16x32).
// Split-K over gridDim.y, plain partial stores (NO atomics).
// blockIdx.z selects {W0,C0} vs {W1,C1} so two GEMMs share one launch.
// ---------------------------------------------------------------------------
__global__ __launch_bounds__(256) void k_gemm(const float* __restrict__ A,
                       const float* __restrict__ W0, float* __restrict__ C0,
                       const float* __restrict__ W1, float* __restrict__ C1,
                       int N, int K, int Kper) {
    const float* __restrict__ W = blockIdx.z ? W1 : W0;
    float* __restrict__ C = blockIdx.z ? C1 : C0;
    __shared__ unsigned short Al[32][136];
    __shared__ unsigned short Wl[64][136];
    const int tid  = threadIdx.x;
    const int lane = tid & 63;
    const int wave = tid >> 6;
    const int quad = lane >> 4;
    const int l16  = lane & 15;
    const int oBlk = blockIdx.x * 64;
    const int k0s  = blockIdx.y * Kper;
    const int ntiles = Kper >> 7;

    f32x4 acc0 = {0.f, 0.f, 0.f, 0.f};
    f32x4 acc1 = {0.f, 0.f, 0.f, 0.f};

    for (int kt = 0; kt < ntiles; ++kt) {
        const int k0 = k0s + kt * 128;
        for (int i = tid; i < 1024; i += 256) {
            const int r = i >> 5, c = i & 31;
            const float4 f = *(const float4*)(A + r * K + k0 + c * 4);
            ushort4 u; u.x = f2bf(f.x); u.y = f2bf(f.y); u.z = f2bf(f.z); u.w = f2bf(f.w);
            *(ushort4*)&Al[r][c * 4] = u;
        }
        for (int i = tid; i < 2048; i += 256) {
            const int r = i >> 5, c = i & 31;
            // W is single-use: keep it out of L2/L3
            const f32x4 f = __builtin_nontemporal_load(
                (const f32x4*)(W + (size_t)(oBlk + r) * K + k0 + c * 4));
            ushort4 u; u.x = f2bf(f[0]); u.y = f2bf(f[1]); u.z = f2bf(f[2]); u.w = f2bf(f[3]);
            *(ushort4*)&Wl[r][c * 4] = u;
        }
        __syncthreads();
        #pragma unroll
        for (int ks = 0; ks < 4; ++ks) {
            const int kk = ks * 32 + quad * 8;
            const short8 a0 = *(const short8*)&Al[l16][kk];
            const short8 a1 = *(const short8*)&Al[16 + l16][kk];
            const short8 wf = *(const short8*)&Wl[wave * 16 + l16][kk];
            acc0 = __builtin_amdgcn_mfma_f32_16x16x32_bf16(a0, wf, acc0, 0, 0, 0);
            acc1 = __builtin_amdgcn_mfma_f32_16x16x32_bf16(a1, wf, acc1, 0, 0, 0);
        }
        __syncthreads();
    }
    const int o = oBlk + wave * 16 + l16;
    float* Cr = C + (size_t)(blockIdx.y * 32) * N + o;
    #pragma unroll
    for (int r = 0; r < 4; ++r) {
        const int b0 = quad * 4 + r;
        Cr[(size_t)b0 * N]        = acc0[r];
        Cr[(size_t)(16 + b0) * N] = acc1[r];
    }
}

// ---------------------------------------------------------------------------
// Reduce x_mlstm partials + causal conv (K=4) + silu; reduce x_gate partials.
// ---------------------------------------------------------------------------
__global__ __launch_bounds__(256) void k_convred(const float* __restrict__ xm_p,
                       const float* __restrict__ xg_p,
                       const float* __restrict__ conv_state,
                       const float* __restrict__ conv_w, const float* __restrict__ conv_b,
                       float* __restrict__ xmc, float* __restrict__ ncs_out,
                       float* __restrict__ x_gate) {
    const int idx = blockIdx.x * 256 + threadIdx.x;      // over B*INNER
    const int c = idx & (INNER_ - 1);
    float xm = 0.f, xg = 0.f;
    #pragma unroll
    for (int s = 0; s < 8; ++s) {
        xm += xm_p[(size_t)s * (B_ * INNER_) + idx];     // (s*32+b)*INNER+c == s*B*INNER+idx
        xg += xg_p[(size_t)s * (B_ * INNER_) + idx];
    }
    x_gate[idx] = xg;
    const float* cs = conv_state + (size_t)idx * 3;
    const float c0 = cs[0], c1 = cs[1], c2 = cs[2];
    const float* w = conv_w + c * 4;
    const float conv = c0 * w[0] + c1 * w[1] + c2 * w[2] + xm * w[3] + conv_b[c];
    xmc[idx] = silu(conv);
    float* no = ncs_out + (size_t)idx * 3;
    no[0] = c1; no[1] = c2; no[2] = xm;
}

// ---------------------------------------------------------------------------
// Reduce qkv split-K partials (8-way) into final qkv. float4 per thread.
// ---------------------------------------------------------------------------
__global__ __launch_bounds__(256) void k_qkvred(const float* __restrict__ qkv_p,
                                                float* __restrict__ qkv) {
    const int e = (blockIdx.x * 256 + threadIdx.x) * 4;  // over B*3*INNER
    float4 s = {0.f, 0.f, 0.f, 0.f};
    #pragma unroll
    for (int p = 0; p < 8; ++p) {
        const float4 v = *(const float4*)(qkv_p + (size_t)p * (B_ * 3 * INNER_) + e);
        s.x += v.x; s.y += v.y; s.z += v.z; s.w += v.w;
    }
    *(float4*)(qkv + e) = s;
}

// ---------------------------------------------------------------------------
// Gates + per-(b,h) scalars + norm_new + qn + denom. One block per (b,h).
// ---------------------------------------------------------------------------
__global__ void k_gates(const float* __restrict__ qkv, const float* __restrict__ Wi,
                        const float* __restrict__ bi, const float* __restrict__ Wf,
                        const float* __restrict__ bfv, const float* __restrict__ max_state,
                        const float* __restrict__ norm_state,
                        float* __restrict__ ig_ws, float* __restrict__ fg_ws,
                        float* __restrict__ max_new, float* __restrict__ norm_out,
                        float* __restrict__ denom_ws) {
    const int bh = blockIdx.x, b = bh >> 3, h = bh & 7, t = threadIdx.x;
    const float* q  = qkv + (size_t)b * (3 * INNER_);
    const float* wi = Wi + (size_t)h * (3 * INNER_);
    const float* wf = Wf + (size_t)h * (3 * INNER_);
    float si = 0.f, sf = 0.f;
    for (int j = t; j < 3 * INNER_; j += 256) {
        const float v = q[j];
        si += v * wi[j];
        sf += v * wf[j];
    }
    __shared__ float r1[4], r2[4], sc[3];
    for (int off = 32; off; off >>= 1) {
        si += __shfl_down(si, off, 64);
        sf += __shfl_down(sf, off, 64);
    }
    if ((t & 63) == 0) { r1[t >> 6] = si; r2[t >> 6] = sf; }
    __syncthreads();
    if (t == 0) {
        float ig = r1[0] + r1[1] + r1[2] + r1[3] + bi[h];
        float fg = r2[0] + r2[1] + r2[2] + r2[3] + bfv[h];
        ig = CAP_ * tanhf(ig / CAP_);
        fg = CAP_ * tanhf(fg / CAP_);
        const float logf_ = (fg >= 0.f) ? -log1pf(expf(-fg)) : (fg - log1pf(expf(fg)));
        const float ms = max_state[bh];
        const float mn = fmaxf(ig, ms + logf_);
        const float i_g = expf(ig - mn);
        const float f_g = expf(logf_ + ms - mn);
        max_new[bh] = mn; ig_ws[bh] = i_g; fg_ws[bh] = f_g;
        sc[0] = i_g; sc[1] = f_g; sc[2] = mn;
    }
    __syncthreads();
    const float i_g = sc[0], f_g = sc[1], mx = sc[2];
    const float rs = 0.044194173824159216f;   // 1/sqrt(512)
    const float* qr = q + h * HEAD_;
    const float* kr = qr + INNER_;
    const float* ns = norm_state + (size_t)bh * HEAD_;
    float qn = 0.f;
    for (int d = t; d < HEAD_; d += 256) {
        const float qv = qr[d];
        const float nn = f_g * ns[d] + i_g * (kr[d] * rs);
        norm_out[(size_t)bh * HEAD_ + d] = nn;
        qn += qv * nn;
    }
    for (int off = 32; off; off >>= 1) qn += __shfl_down(qn, off, 64);
    if ((t & 63) == 0) r1[t >> 6] = qn;
    __syncthreads();
    if (t == 0) {
        const float q_total = r1[0] + r1[1] + r1[2] + r1[3];
        denom_ws[bh] = fmaxf(fabsf(q_total), expf(-mx)) + 1e-6f;
    }
}

// ---------------------------------------------------------------------------
// Streaming cell update + partial numer. Grid = B*NH*8 (64 d-rows per block).
// Non-temporal on the 536 MB single-use cell stream; partial stores, no atomics.
// ---------------------------------------------------------------------------
__global__ __launch_bounds__(256) void k_cell(const float* __restrict__ qkv,
                       const float* __restrict__ ig_ws, const float* __restrict__ fg_ws,
                       const float* __restrict__ cell_state,
                       float* __restrict__ cell_out, float* __restrict__ numer_p) {
    const int blk = blockIdx.x;
    const int bh = blk >> 3, chunk = blk & 7;
    const int b = bh >> 3, h = bh & 7, t = threadIdx.x;
    const int d0 = chunk * DCH_;
    __shared__ float q_l[DCH_], ik_l[DCH_];
    __shared__ float nred[HEAD_];
    const float i_g = ig_ws[bh], f_g = fg_ws[bh];
    const float rs = 0.044194173824159216f;
    const float* qr = qkv + (size_t)b * (3 * INNER_) + h * HEAD_;
    const float* kr = qr + INNER_;
    const float* vr = qr + 2 * INNER_;
    if (t < DCH_) {
        q_l[t]  = qr[d0 + t];
        ik_l[t] = i_g * (kr[d0 + t] * rs);
    }
    __syncthreads();
    const int half = t >> 7;
    const int col  = (t & 127) * 4;
    const float4 v4 = *(const float4*)(vr + col);
    const float* pin  = cell_state + (size_t)bh * HEAD_ * HEAD_ + (size_t)(d0 + half) * HEAD_ + col;
    float*       pout = cell_out   + (size_t)bh * HEAD_ * HEAD_ + (size_t)(d0 + half) * HEAD_ + col;
    float4 num = {0.f, 0.f, 0.f, 0.f};
    #pragma unroll 8
    for (int it = 0; it < DCH_ / 2; ++it) {
        const int d = it * 2 + half;
        const f32x4 c4 = __builtin_nontemporal_load((const f32x4*)pin);
        const float ik = ik_l[d], qv = q_l[d];
        f32x4 cn;
        cn[0] = f_g * c4[0] + ik * v4.x;
        cn[1] = f_g * c4[1] + ik * v4.y;
        cn[2] = f_g * c4[2] + ik * v4.z;
        cn[3] = f_g * c4[3] + ik * v4.w;
        __builtin_nontemporal_store(cn, (f32x4*)pout);
        num.x += qv * cn[0]; num.y += qv * cn[1]; num.z += qv * cn[2]; num.w += qv * cn[3];
        pin  += 2 * HEAD_;
        pout += 2 * HEAD_;
    }
    if (half == 0) {
        *(float4*)&nred[col] = *(float4*)&num;
    }
    __syncthreads();
    if (half == 1) {
        float4 tot;
        tot.x = nred[col]     + num.x;
        tot.y = nred[col + 1] + num.y;
        tot.z = nred[col + 2] + num.z;
        tot.w = nred[col + 3] + num.w;
        *(float4*)(numer_p + ((size_t)bh * 8 + chunk) * HEAD_ + col) = tot;
    }
}

// ---------------------------------------------------------------------------
// Epilogue: reduce numer partials (8-way) + groupnorm + skip + gate -> h.
// One block per (b,h).
// ---------------------------------------------------------------------------
__global__ void k_epi(const float* __restrict__ numer_p, const float* __restrict__ denom_ws,
                      const float* __restrict__ gn_w, const float* __restrict__ gn_b,
                      const float* __restrict__ skip_w, const float* __restrict__ xmc,
                      const float* __restrict__ x_gate, float* __restrict__ h_out) {
    const int bh = blockIdx.x, b = bh >> 3, h = bh & 7, t = threadIdx.x;
    __shared__ float redA[4], redB[4];
    __shared__ float nu_s[HEAD_];
    const float inv_d = 1.0f / denom_ws[bh];
    const float* np = numer_p + (size_t)bh * 8 * HEAD_;
    float s = 0.f, s2 = 0.f;
    for (int e = t; e < HEAD_; e += 256) {
        float nu = 0.f;
        #pragma unroll
        for (int c = 0; c < 8; ++c) nu += np[c * HEAD_ + e];
        const float o = nu * inv_d;
        nu_s[e] = o;
        s += o; s2 += o * o;
    }
    for (int off = 32; off; off >>= 1) {
        s  += __shfl_down(s, off, 64);
        s2 += __shfl_down(s2, off, 64);
    }
    if ((t & 63) == 0) { redA[t >> 6] = s; redB[t >> 6] = s2; }
    __syncthreads();
    const float mu  = (redA[0] + redA[1] + redA[2] + redA[3]) / (float)HEAD_;
    const float ex2 = (redB[0] + redB[1] + redB[2] + redB[3]) / (float)HEAD_;
    const float inv = rsqrtf(fmaxf(ex2 - mu * mu, 0.f) + 1e-5f);
    for (int e = t; e < HEAD_; e += 256) {
        const int i = h * HEAD_ + e;
        const float og = (nu_s[e] - mu) * inv * gn_w[i] + gn_b[i];
        const float xg = x_gate[(size_t)b * INNER_ + i];
        const float hv = (og + skip_w[i] * xmc[(size_t)b * INNER_ + i]) * silu(xg);
        h_out[(size_t)b * INNER_ + i] = hv;
    }
}

// ---------------------------------------------------------------------------
// Final y = x + sum_{16 splits} down-partials.
// ---------------------------------------------------------------------------
__global__ __launch_bounds__(256) void k_yred(const float* __restrict__ y_p,
                                              const float* __restrict__ x,
                                              float* __restrict__ y) {
    const int e = (blockIdx.x * 256 + threadIdx.x) * 4;   // over B*HID
    float4 s = *(const float4*)(x + e);
    #pragma unroll
    for (int p = 0; p < 16; ++p) {
        const float4 v = *(const float4*)(y_p + (size_t)p * (B_ * HID_) + e);
        s.x += v.x; s.y += v.y; s.z += v.z; s.w += v.w;
    }
    *(float4*)(y + e) = s;
}

// ---------------------------------------------------------------------------
extern "C" void kernel_launch(void* const* d_in, const int* in_sizes, int n_in,
                              void* d_out, int out_size, void* d_ws, size_t ws_size,
                              hipStream_t stream) {
    const float* x          = (const float*)d_in[0];
    const float* conv_state = (const float*)d_in[1];
    const float* cell_state = (const float*)d_in[2];
    const float* norm_state = (const float*)d_in[3];
    const float* max_state  = (const float*)d_in[4];
    const float* rms_w      = (const float*)d_in[5];
    const float* Wx         = (const float*)d_in[6];
    const float* Wg         = (const float*)d_in[7];
    const float* Wqkv       = (const float*)d_in[8];
    const float* conv_w     = (const float*)d_in[9];
    const float* conv_b     = (const float*)d_in[10];
    const float* Wi         = (const float*)d_in[11];
    const float* bi         = (const float*)d_in[12];
    const float* Wf         = (const float*)d_in[13];
    const float* bfv        = (const float*)d_in[14];
    const float* gn_w       = (const float*)d_in[15];
    const float* gn_b       = (const float*)d_in[16];
    const float* Wdown      = (const float*)d_in[17];
    const float* skip_w     = (const float*)d_in[18];

    float* out = (float*)d_out;
    float* y_out    = out;                                   // 32*2048
    float* ncs_out  = y_out + B_ * HID_;                     // 32*4096*3
    float* cell_out = ncs_out + (size_t)B_ * INNER_ * 3;     // 32*8*512*512
    float* norm_out = cell_out + (size_t)B_ * NH_ * HEAD_ * HEAD_;
    float* max_out  = norm_out + (size_t)B_ * NH_ * HEAD_;

    float* w = (float*)d_ws;
    float* xn       = w;                          // 65536
    float* xmc      = xn + B_ * HID_;             // 131072
    float* h_ws     = xmc + B_ * INNER_;          // 131072
    float* x_gate   = h_ws + B_ * INNER_;         // 131072
    float* ig_ws    = x_gate + B_ * INNER_;       // 256
    float* fg_ws    = ig_ws + B_ * NH_;           // 256
    float* denom_ws = fg_ws + B_ * NH_;           // 256
    float* qkv      = denom_ws + B_ * NH_;        // 393216
    float* xm_p     = qkv + B_ * 3 * INNER_;      // 8*131072
    float* xg_p     = xm_p + 8 * B_ * INNER_;     // 8*131072
    float* qkv_p    = xg_p + 8 * B_ * INNER_;     // 8*393216
    float* y_p      = qkv_p + (size_t)8 * B_ * 3 * INNER_;   // 16*65536
    float* numer_p  = y_p + 16 * B_ * HID_;       // 2048*512
    // total ws ≈ 8.06M floats ≈ 32.3 MB — no zero-init required anywhere.

    k_rms<<<B_, 256, 0, stream>>>(x, rms_w, xn);

    // Wx and Wg share one launch (blockIdx.z selects), split-K=8 partials.
    k_gemm<<<dim3(INNER_ / 64, 8, 2), 256, 0, stream>>>(xn, Wx, xm_p, Wg, xg_p,
                                                        INNER_, HID_, HID_ / 8);

    k_convred<<<(B_ * INNER_) / 256, 256, 0, stream>>>(xm_p, xg_p, conv_state,
                                                       conv_w, conv_b, xmc, ncs_out, x_gate);

    k_gemm<<<dim3(3 * INNER_ / 64, 8, 1), 256, 0, stream>>>(xmc, Wqkv, qkv_p, Wqkv, qkv_p,
                                                            3 * INNER_, INNER_, INNER_ / 8);

    k_qkvred<<<(B_ * 3 * INNER_) / 1024, 256, 0, stream>>>(qkv_p, qkv);

    k_gates<<<B_ * NH_, 256, 0, stream>>>(qkv, Wi, bi, Wf, bfv, max_state, norm_state,
                                          ig_ws, fg_ws, max_out, norm_out, denom_ws);

    k_cell<<<B_ * NH_ * 8, 256, 0, stream>>>(qkv, ig_ws, fg_ws, cell_state,
                                             cell_out, numer_p);

    k_epi<<<B_ * NH_, 256, 0, stream>>>(numer_p, denom_ws, gn_w, gn_b, skip_w,
                                        xmc, x_gate, h_ws);

    k_gemm<<<dim3(HID_ / 64, 16, 1), 256, 0, stream>>>(h_ws, Wdown, y_p, Wdown, y_p,
                                                       HID_, INNER_, INNER_ / 16);

    k_yred<<<(B_ * HID_) / 1024, 256, 0, stream>>>(y_p, x, y_out);
}